// Round 1
// baseline (2050.107 us; speedup 1.0000x reference)
//
#include <hip/hip_runtime.h>
#include <hip/hip_bf16.h>

typedef __bf16 bf16_t;
typedef bf16_t bf16x8 __attribute__((ext_vector_type(8)));
typedef float f32x4 __attribute__((ext_vector_type(4)));
typedef unsigned short u16;
typedef unsigned int u32;

__device__ __forceinline__ u16 f2bf(float f) {
    __hip_bfloat16 h = __float2bfloat16(f);
    return __builtin_bit_cast(u16, h);
}
__device__ __forceinline__ float bf2f(u16 u) {
    u32 x = ((u32)u) << 16;
    return __builtin_bit_cast(float, x);
}
__device__ __forceinline__ float softthr(float v, float l) {
    return copysignf(fmaxf(fabsf(v) - l, 0.0f), v);
}

// ---- prep: Dict copy to out[2], Dict_bf [128][512], DictT_bf [512][128] ----
__global__ __launch_bounds__(256) void prep_dict(const float* __restrict__ Dict,
                                                 float* __restrict__ outd,
                                                 u16* __restrict__ Dictb,
                                                 u16* __restrict__ DictT)
{
    int i = blockIdx.x * 256 + threadIdx.x;   // 65536 total
    float v = Dict[i];
    outd[i] = v;
    Dictb[i] = f2bf(v);
    int d = i >> 9, a = i & 511;
    DictT[(a << 7) + d] = f2bf(v);
}

// ---- prep: Gm = bf16( -(Dict^T Dict) / L )  [512][512] (symmetric) ----
__global__ __launch_bounds__(256) void prep_gram(const float* __restrict__ Dict,
                                                 const float* __restrict__ Lp,
                                                 u16* __restrict__ Gm)
{
    int idx = blockIdx.x * 256 + threadIdx.x;   // 262144 total
    int i = idx >> 9, j = idx & 511;
    float s = 0.0f;
    for (int d = 0; d < 128; ++d)
        s = fmaf(Dict[(d << 9) + i], Dict[(d << 9) + j], s);
    Gm[idx] = f2bf(-s / Lp[0]);
}

// ---- fused LISTA: 64 pixels per block, 4 waves (N-split 128 cols each) ----
__global__ __launch_bounds__(256, 1)
void lista_main(const float* __restrict__ x,
                const float* __restrict__ alpha,
                const float* __restrict__ Lp,
                const int* __restrict__ nip,
                const u16* __restrict__ Gm,     // -G/L  bf16 [512][512]
                const u16* __restrict__ DictT,  // bf16 [512][128]
                const u16* __restrict__ Dictb,  // bf16 [128][512]
                float* __restrict__ outz,       // [32][512][1024]
                float* __restrict__ outr)       // [32][128][1024]
{
    __shared__ __align__(16) u16 zl[64 * 512];   // 64 KB: z bf16 (first 16KB reused for x staging)
    __shared__ __align__(16) uint2 wl[8192];     // 64 KB: w = y/L bf16, lane-linear layout

    const int t = threadIdx.x;
    const int lane = t & 63;
    const int wave = t >> 6;
    const int l15 = lane & 15;
    const int lg = lane >> 4;          // 0..3
    const int pb = blockIdx.x;
    const int p0 = pb << 6;
    const int bb = p0 >> 10;           // batch index
    const int hw0 = p0 & 1023;         // pixel base within batch
    const float invL = 1.0f / Lp[0];
    const int niter = nip[0];
    const int cb = wave << 7;          // wave column base in [0,512)

    // per-lane soft-threshold values for its 16 rows (alpha[hw]/L)
    float lthr[4][4];
#pragma unroll
    for (int mt = 0; mt < 4; ++mt)
#pragma unroll
        for (int r = 0; r < 4; ++r)
            lthr[mt][r] = alpha[hw0 + mt * 16 + lg * 4 + r] * invL;

    // ---- stage x -> bf16 [64 rows][128 dims] (swizzled) in zl's first 16KB ----
#pragma unroll 4
    for (int i = t; i < 64 * 128; i += 256) {
        int d = i >> 6, r = i & 63;
        float v = x[((bb * 128 + d) << 10) + hw0 + r];
        int idx = (r << 7) + d;
        zl[idx ^ ((r & 7) << 3)] = f2bf(v);
    }
    __syncthreads();

    // ---- y = x @ Dict   (M=64, N=128/wave, K=128) ----
    f32x4 acc[4][8];
#pragma unroll
    for (int mt = 0; mt < 4; ++mt)
#pragma unroll
        for (int nt = 0; nt < 8; ++nt)
            acc[mt][nt] = f32x4{0.f, 0.f, 0.f, 0.f};

#pragma unroll
    for (int kt = 0; kt < 4; ++kt) {
        const int k0 = kt * 32 + lg * 8;
        bf16x8 Af[4];
#pragma unroll
        for (int mt = 0; mt < 4; ++mt) {
            int row = mt * 16 + l15;
            int idx = (row << 7) + k0;
            Af[mt] = *reinterpret_cast<const bf16x8*>(&zl[idx ^ ((row & 7) << 3)]);
        }
        bf16x8 Bf[8];
#pragma unroll
        for (int nt = 0; nt < 8; ++nt) {
            int j = cb + nt * 16 + l15;
            Bf[nt] = *reinterpret_cast<const bf16x8*>(&DictT[(j << 7) + k0]);
        }
#pragma unroll
        for (int nt = 0; nt < 8; ++nt)
#pragma unroll
            for (int mt = 0; mt < 4; ++mt)
                acc[mt][nt] = __builtin_amdgcn_mfma_f32_16x16x32_bf16(Af[mt], Bf[nt], acc[mt][nt], 0, 0, 0);
    }
    __syncthreads();   // all waves done reading x staging before overwriting zl

    // ---- z0 = ST(y); w = y/L -> LDS; keep fp32 z copy in regs ----
    f32x4 zf[4][8];
#pragma unroll
    for (int mt = 0; mt < 4; ++mt) {
#pragma unroll
        for (int nt = 0; nt < 8; ++nt) {
            f32x4 y = acc[mt][nt];
            uint2 wp;
            wp.x = (u32)f2bf(y[0] * invL) | ((u32)f2bf(y[1] * invL) << 16);
            wp.y = (u32)f2bf(y[2] * invL) | ((u32)f2bf(y[3] * invL) << 16);
            wl[((wave * 4 + mt) * 8 + nt) * 64 + lane] = wp;
            int col = cb + nt * 16 + l15;
#pragma unroll
            for (int r = 0; r < 4; ++r) {
                float z = softthr(y[r], lthr[mt][r]);
                zf[mt][nt][r] = z;
                int row = mt * 16 + lg * 4 + r;
                int idx = (row << 9) + col;
                zl[idx ^ ((row & 7) << 3)] = f2bf(z);
            }
        }
    }
    __syncthreads();

    // ---- main loop: z = ST( z + w + z_bf @ (-G/L) ) ----
    for (int it = 0; it < niter; ++it) {
        // acc = zf (exact fp32 self term) + w
#pragma unroll
        for (int mt = 0; mt < 4; ++mt)
#pragma unroll
            for (int nt = 0; nt < 8; ++nt) {
                uint2 wp = wl[((wave * 4 + mt) * 8 + nt) * 64 + lane];
                f32x4 a;
                a[0] = zf[mt][nt][0] + bf2f((u16)(wp.x & 0xffffu));
                a[1] = zf[mt][nt][1] + bf2f((u16)(wp.x >> 16));
                a[2] = zf[mt][nt][2] + bf2f((u16)(wp.y & 0xffffu));
                a[3] = zf[mt][nt][3] + bf2f((u16)(wp.y >> 16));
                acc[mt][nt] = a;
            }
        // acc += z_bf @ (-G/L),  K = 512
#pragma unroll
        for (int kt = 0; kt < 16; ++kt) {
            const int k0 = kt * 32 + lg * 8;
            bf16x8 Af[4];
#pragma unroll
            for (int mt = 0; mt < 4; ++mt) {
                int row = mt * 16 + l15;
                int idx = (row << 9) + k0;
                Af[mt] = *reinterpret_cast<const bf16x8*>(&zl[idx ^ ((row & 7) << 3)]);
            }
            bf16x8 Bf[8];
#pragma unroll
            for (int nt = 0; nt < 8; ++nt) {
                int j = cb + nt * 16 + l15;
                Bf[nt] = *reinterpret_cast<const bf16x8*>(&Gm[(j << 9) + k0]);
            }
#pragma unroll
            for (int nt = 0; nt < 8; ++nt)
#pragma unroll
                for (int mt = 0; mt < 4; ++mt)
                    acc[mt][nt] = __builtin_amdgcn_mfma_f32_16x16x32_bf16(Af[mt], Bf[nt], acc[mt][nt], 0, 0, 0);
        }
        __syncthreads();   // all waves finished reading zl
        // threshold, update fp32 copy, write bf16 z back to LDS
#pragma unroll
        for (int mt = 0; mt < 4; ++mt)
#pragma unroll
            for (int nt = 0; nt < 8; ++nt) {
                int col = cb + nt * 16 + l15;
#pragma unroll
                for (int r = 0; r < 4; ++r) {
                    float z = softthr(acc[mt][nt][r], lthr[mt][r]);
                    zf[mt][nt][r] = z;
                    int row = mt * 16 + lg * 4 + r;
                    int idx = (row << 9) + col;
                    zl[idx ^ ((row & 7) << 3)] = f2bf(z);
                }
            }
        __syncthreads();
    }

    // ---- x_recon = z @ Dict^T  (N=128 total, 32 cols/wave, K=512) ----
    f32x4 racc[4][2];
#pragma unroll
    for (int mt = 0; mt < 4; ++mt)
#pragma unroll
        for (int n2 = 0; n2 < 2; ++n2)
            racc[mt][n2] = f32x4{0.f, 0.f, 0.f, 0.f};
    const int cb2 = wave << 5;
#pragma unroll
    for (int kt = 0; kt < 16; ++kt) {
        const int k0 = kt * 32 + lg * 8;
        bf16x8 Af[4];
#pragma unroll
        for (int mt = 0; mt < 4; ++mt) {
            int row = mt * 16 + l15;
            int idx = (row << 9) + k0;
            Af[mt] = *reinterpret_cast<const bf16x8*>(&zl[idx ^ ((row & 7) << 3)]);
        }
#pragma unroll
        for (int n2 = 0; n2 < 2; ++n2) {
            int j = cb2 + n2 * 16 + l15;
            bf16x8 Bf = *reinterpret_cast<const bf16x8*>(&Dictb[(j << 9) + k0]);
#pragma unroll
            for (int mt = 0; mt < 4; ++mt)
                racc[mt][n2] = __builtin_amdgcn_mfma_f32_16x16x32_bf16(Af[mt], Bf, racc[mt][n2], 0, 0, 0);
        }
    }

    // write x_recon to wl region as fp32 [64][128] (swizzled) for coalesced store
    float* wf = reinterpret_cast<float*>(wl);
#pragma unroll
    for (int mt = 0; mt < 4; ++mt)
#pragma unroll
        for (int n2 = 0; n2 < 2; ++n2) {
            int dl = cb2 + n2 * 16 + l15;
#pragma unroll
            for (int r = 0; r < 4; ++r) {
                int row = mt * 16 + lg * 4 + r;
                int idx = (row << 7) + dl;
                wf[idx ^ ((row & 7) << 2)] = racc[mt][n2][r];
            }
        }

    // ---- store z (from LDS bf16), coalesced 256B segments ----
#pragma unroll 4
    for (int i = t; i < 64 * 512; i += 256) {
        int a = i >> 6, r = i & 63;
        int idx = (r << 9) + a;
        outz[((bb * 512 + a) << 10) + hw0 + r] = bf2f(zl[idx ^ ((r & 7) << 3)]);
    }
    __syncthreads();
    // ---- store x_recon, coalesced ----
#pragma unroll 4
    for (int i = t; i < 64 * 128; i += 256) {
        int d = i >> 6, r = i & 63;
        int idx = (r << 7) + d;
        outr[((bb * 128 + d) << 10) + hw0 + r] = wf[idx ^ ((r & 7) << 2)];
    }
}

extern "C" void kernel_launch(void* const* d_in, const int* in_sizes, int n_in,
                              void* d_out, int out_size, void* d_ws, size_t ws_size,
                              hipStream_t stream)
{
    const float* x     = (const float*)d_in[0];
    const float* Dict  = (const float*)d_in[1];
    const float* alpha = (const float*)d_in[2];
    const float* Lp    = (const float*)d_in[3];
    const int*   nip   = (const int*)d_in[4];

    float* outz = (float*)d_out;                 // [32,512,32,32]
    float* outr = outz + 32 * 512 * 1024;        // [32,128,32,32]
    float* outd = outr + 32 * 128 * 1024;        // [128,512]

    u16* Gm    = (u16*)d_ws;                     // 512*512 bf16
    u16* DictT = Gm + 512 * 512;                 // 512*128 bf16
    u16* Dictb = DictT + 512 * 128;              // 128*512 bf16

    prep_dict<<<dim3(256), dim3(256), 0, stream>>>(Dict, outd, Dictb, DictT);
    prep_gram<<<dim3(1024), dim3(256), 0, stream>>>(Dict, Lp, Gm);
    lista_main<<<dim3(512), dim3(256), 0, stream>>>(x, alpha, Lp, nip,
                                                    Gm, DictT, Dictb, outz, outr);
}

// Round 2
// 1347.053 us; speedup vs baseline: 1.5219x; 1.5219x over previous
//
#include <hip/hip_runtime.h>
#include <hip/hip_bf16.h>

typedef __bf16 bf16_t;
typedef bf16_t bf16x8 __attribute__((ext_vector_type(8)));
typedef float f32x4 __attribute__((ext_vector_type(4)));
typedef unsigned short u16;
typedef unsigned int u32;

__device__ __forceinline__ u16 f2bf(float f) {
    __hip_bfloat16 h = __float2bfloat16(f);
    return __builtin_bit_cast(u16, h);
}
__device__ __forceinline__ float bf2f(u16 u) {
    u32 x = ((u32)u) << 16;
    return __builtin_bit_cast(float, x);
}
__device__ __forceinline__ float softthr(float v, float l) {
    return copysignf(fmaxf(fabsf(v) - l, 0.0f), v);
}

// ---- prep: Dict copy to out[2], Dict_bf [128][512], DictT_bf [512][128] ----
__global__ __launch_bounds__(256) void prep_dict(const float* __restrict__ Dict,
                                                 float* __restrict__ outd,
                                                 u16* __restrict__ Dictb,
                                                 u16* __restrict__ DictT)
{
    int i = blockIdx.x * 256 + threadIdx.x;   // 65536 total
    float v = Dict[i];
    outd[i] = v;
    Dictb[i] = f2bf(v);
    int d = i >> 9, a = i & 511;
    DictT[(a << 7) + d] = f2bf(v);
}

// ---- prep: Gm = bf16( -(Dict^T Dict) / L )  [512][512] (symmetric) ----
__global__ __launch_bounds__(256) void prep_gram(const float* __restrict__ Dict,
                                                 const float* __restrict__ Lp,
                                                 u16* __restrict__ Gm)
{
    int idx = blockIdx.x * 256 + threadIdx.x;   // 262144 total
    int i = idx >> 9, j = idx & 511;
    float s = 0.0f;
    for (int d = 0; d < 128; ++d)
        s = fmaf(Dict[(d << 9) + i], Dict[(d << 9) + j], s);
    Gm[idx] = f2bf(-s / Lp[0]);
}

// ---- fused LISTA: 128 pixels/block, 8 waves (2M x 4N), acc == fp32 z ----
__global__ __launch_bounds__(512, 2)
void lista_main(const float* __restrict__ x,
                const float* __restrict__ alpha,
                const float* __restrict__ Lp,
                const int* __restrict__ nip,
                const u16* __restrict__ Gm,     // -G/L  bf16 [512][512]
                const u16* __restrict__ DictT,  // bf16 [512][128]
                const u16* __restrict__ Dictb,  // bf16 [128][512]
                float* __restrict__ outz,       // [32][512][1024]
                float* __restrict__ outr)       // [32][128][1024]
{
    __shared__ __align__(16) u16 zl[128 * 512];   // 128 KB z bf16 (front reused for x / recon staging)
    __shared__ float thr_lds[128];

    const int t = threadIdx.x;
    const int lane = t & 63;
    const int wave = t >> 6;
    const int l15 = lane & 15;
    const int lg = lane >> 4;            // 0..3
    const int wm = wave >> 2;            // 0..1 : pixel half
    const int wn = wave & 3;             // 0..3 : column quarter
    const int pb = blockIdx.x;
    const int bb = pb >> 3;              // batch index
    const int hw0 = (pb & 7) << 7;       // 128-pixel base within batch
    const float invL = 1.0f / Lp[0];
    const int niter = nip[0];
    const int rb = wm << 6;              // wave pixel base
    const int cb = wn << 7;              // wave column base

    if (t < 128) thr_lds[t] = alpha[hw0 + t] * invL;

    // ---- stage x -> bf16 [128 pix][128 d] (swizzled) in zl front ----
    for (int i = t; i < 128 * 128; i += 512) {
        int d = i >> 7, r = i & 127;
        float v = __builtin_nontemporal_load(&x[((bb * 128 + d) << 10) + hw0 + r]);
        int idx = (r << 7) + d;
        zl[idx ^ ((r & 7) << 3)] = f2bf(v);
    }
    __syncthreads();

    // ---- y = x @ Dict  (wave tile: 64 pix x 128 cols, K=128) ----
    f32x4 acc[4][8];
#pragma unroll
    for (int mt = 0; mt < 4; ++mt)
#pragma unroll
        for (int nt = 0; nt < 8; ++nt)
            acc[mt][nt] = f32x4{0.f, 0.f, 0.f, 0.f};

#pragma unroll
    for (int kt = 0; kt < 4; ++kt) {
        const int k0 = kt * 32 + lg * 8;
        bf16x8 Af[4];
#pragma unroll
        for (int mt = 0; mt < 4; ++mt) {
            int row = rb + mt * 16 + l15;
            int idx = (row << 7) + k0;
            Af[mt] = *reinterpret_cast<const bf16x8*>(&zl[idx ^ ((row & 7) << 3)]);
        }
#pragma unroll
        for (int h = 0; h < 2; ++h) {
            bf16x8 Bf[4];
#pragma unroll
            for (int q = 0; q < 4; ++q) {
                int j = cb + (h * 4 + q) * 16 + l15;
                Bf[q] = *reinterpret_cast<const bf16x8*>(&DictT[(j << 7) + k0]);
            }
#pragma unroll
            for (int q = 0; q < 4; ++q)
#pragma unroll
                for (int mt = 0; mt < 4; ++mt)
                    acc[mt][h * 4 + q] = __builtin_amdgcn_mfma_f32_16x16x32_bf16(Af[mt], Bf[q], acc[mt][h * 4 + q], 0, 0, 0);
        }
    }
    __syncthreads();   // done reading x staging before overwriting zl

    // ---- z0 = ST(y); w = y/L packed bf16 in regs; acc becomes fp32 z ----
    uint2 wpk[4][8];
#pragma unroll
    for (int mt = 0; mt < 4; ++mt) {
#pragma unroll
        for (int nt = 0; nt < 8; ++nt) {
            f32x4 y = acc[mt][nt];
            uint2 wp;
            wp.x = (u32)f2bf(y[0] * invL) | ((u32)f2bf(y[1] * invL) << 16);
            wp.y = (u32)f2bf(y[2] * invL) | ((u32)f2bf(y[3] * invL) << 16);
            wpk[mt][nt] = wp;
            int col = cb + nt * 16 + l15;
#pragma unroll
            for (int r = 0; r < 4; ++r) {
                int row = rb + mt * 16 + lg * 4 + r;
                float z = softthr(y[r], thr_lds[row]);
                acc[mt][nt][r] = z;
                int idx = (row << 9) + col;
                zl[idx ^ ((row & 7) << 3)] = f2bf(z);
            }
        }
    }
    __syncthreads();

    // ---- main loop: acc(z fp32) += w + z_bf @ (-G/L); threshold in place ----
    for (int it = 0; it < niter; ++it) {
#pragma unroll
        for (int mt = 0; mt < 4; ++mt)
#pragma unroll
            for (int nt = 0; nt < 8; ++nt) {
                uint2 wp = wpk[mt][nt];
                acc[mt][nt][0] += bf2f((u16)(wp.x & 0xffffu));
                acc[mt][nt][1] += bf2f((u16)(wp.x >> 16));
                acc[mt][nt][2] += bf2f((u16)(wp.y & 0xffffu));
                acc[mt][nt][3] += bf2f((u16)(wp.y >> 16));
            }
#pragma unroll 2
        for (int kt = 0; kt < 16; ++kt) {
            const int k0 = kt * 32 + lg * 8;
            bf16x8 Af[4];
#pragma unroll
            for (int mt = 0; mt < 4; ++mt) {
                int row = rb + mt * 16 + l15;
                int idx = (row << 9) + k0;
                Af[mt] = *reinterpret_cast<const bf16x8*>(&zl[idx ^ ((row & 7) << 3)]);
            }
#pragma unroll
            for (int h = 0; h < 2; ++h) {
                bf16x8 Bf[4];
#pragma unroll
                for (int q = 0; q < 4; ++q) {
                    int j = cb + (h * 4 + q) * 16 + l15;
                    Bf[q] = *reinterpret_cast<const bf16x8*>(&Gm[(j << 9) + k0]);
                }
#pragma unroll
                for (int q = 0; q < 4; ++q)
#pragma unroll
                    for (int mt = 0; mt < 4; ++mt)
                        acc[mt][h * 4 + q] = __builtin_amdgcn_mfma_f32_16x16x32_bf16(Af[mt], Bf[q], acc[mt][h * 4 + q], 0, 0, 0);
            }
        }
        __syncthreads();   // all waves finished reading zl
#pragma unroll
        for (int mt = 0; mt < 4; ++mt)
#pragma unroll
            for (int nt = 0; nt < 8; ++nt) {
                int col = cb + nt * 16 + l15;
#pragma unroll
                for (int r = 0; r < 4; ++r) {
                    int row = rb + mt * 16 + lg * 4 + r;
                    float z = softthr(acc[mt][nt][r], thr_lds[row]);
                    acc[mt][nt][r] = z;
                    int idx = (row << 9) + col;
                    zl[idx ^ ((row & 7) << 3)] = f2bf(z);
                }
            }
        __syncthreads();
    }

    // ---- x_recon = z @ Dict^T  (wave tile: 64 pix x 32 dims, K=512) ----
    f32x4 racc[4][2];
#pragma unroll
    for (int mt = 0; mt < 4; ++mt)
#pragma unroll
        for (int n2 = 0; n2 < 2; ++n2)
            racc[mt][n2] = f32x4{0.f, 0.f, 0.f, 0.f};
    const int cb2 = wn << 5;
#pragma unroll 2
    for (int kt = 0; kt < 16; ++kt) {
        const int k0 = kt * 32 + lg * 8;
        bf16x8 Af[4];
#pragma unroll
        for (int mt = 0; mt < 4; ++mt) {
            int row = rb + mt * 16 + l15;
            int idx = (row << 9) + k0;
            Af[mt] = *reinterpret_cast<const bf16x8*>(&zl[idx ^ ((row & 7) << 3)]);
        }
#pragma unroll
        for (int n2 = 0; n2 < 2; ++n2) {
            int j = cb2 + n2 * 16 + l15;
            bf16x8 Bf = *reinterpret_cast<const bf16x8*>(&Dictb[(j << 9) + k0]);
#pragma unroll
            for (int mt = 0; mt < 4; ++mt)
                racc[mt][n2] = __builtin_amdgcn_mfma_f32_16x16x32_bf16(Af[mt], Bf, racc[mt][n2], 0, 0, 0);
        }
    }

    // ---- store z from LDS (nontemporal, coalesced 512B per row-group) ----
    for (int i = t; i < 128 * 512; i += 512) {
        int a = i >> 7, r = i & 127;
        int idx = (r << 9) + a;
        float zv = bf2f(zl[idx ^ ((r & 7) << 3)]);
        __builtin_nontemporal_store(zv, &outz[((bb * 512 + a) << 10) + hw0 + r]);
    }
    __syncthreads();   // z reads done before overwriting zl with recon

    // ---- stage x_recon fp32 [128 pix][128 d] (swizzled) in zl front ----
    float* wf = reinterpret_cast<float*>(zl);
#pragma unroll
    for (int mt = 0; mt < 4; ++mt)
#pragma unroll
        for (int n2 = 0; n2 < 2; ++n2) {
            int dl = cb2 + n2 * 16 + l15;
#pragma unroll
            for (int r = 0; r < 4; ++r) {
                int row = rb + mt * 16 + lg * 4 + r;
                int idx = (row << 7) + dl;
                wf[idx ^ ((row & 7) << 2)] = racc[mt][n2][r];
            }
        }
    __syncthreads();

    // ---- store x_recon (nontemporal, coalesced) ----
    for (int i = t; i < 128 * 128; i += 512) {
        int d = i >> 7, r = i & 127;
        int idx = (r << 7) + d;
        __builtin_nontemporal_store(wf[idx ^ ((r & 7) << 2)],
                                    &outr[((bb * 128 + d) << 10) + hw0 + r]);
    }
}

extern "C" void kernel_launch(void* const* d_in, const int* in_sizes, int n_in,
                              void* d_out, int out_size, void* d_ws, size_t ws_size,
                              hipStream_t stream)
{
    const float* x     = (const float*)d_in[0];
    const float* Dict  = (const float*)d_in[1];
    const float* alpha = (const float*)d_in[2];
    const float* Lp    = (const float*)d_in[3];
    const int*   nip   = (const int*)d_in[4];

    float* outz = (float*)d_out;                 // [32,512,32,32]
    float* outr = outz + 32 * 512 * 1024;        // [32,128,32,32]
    float* outd = outr + 32 * 128 * 1024;        // [128,512]

    u16* Gm    = (u16*)d_ws;                     // 512*512 bf16
    u16* DictT = Gm + 512 * 512;                 // 512*128 bf16
    u16* Dictb = DictT + 512 * 128;              // 128*512 bf16

    prep_dict<<<dim3(256), dim3(256), 0, stream>>>(Dict, outd, Dictb, DictT);
    prep_gram<<<dim3(1024), dim3(256), 0, stream>>>(Dict, Lp, Gm);
    lista_main<<<dim3(256), dim3(512), 0, stream>>>(x, alpha, Lp, nip,
                                                    Gm, DictT, Dictb, outz, outr);
}